// Round 3
// baseline (75.289 us; speedup 1.0000x reference)
//
#include <hip/hip_runtime.h>
#include <hip/hip_bf16.h>
#include <math.h>

#define Bc 2
#define Cc 16
#define D4c 48
#define Kc 24
#define Hc 512
#define Wc 960
#define H4c 128
#define W4c 240
#define HW4 (H4c * W4c)   // 30720
#define S4 (Bc * HW4)     // 61440
#define HW1 (Hc * Wc)     // 491520
#define S1 (Bc * HW1)     // 983040

// ---------------------------------------------------------------------------
// Kernel A: channel-reduce feat_l/feat_r with w_red -> Lred[p], Rred[p]
// ---------------------------------------------------------------------------
__global__ void k_featred(const float* __restrict__ fl, const float* __restrict__ fr,
                          const float* __restrict__ wred,
                          float* __restrict__ Lred, float* __restrict__ Rred) {
    int p = blockIdx.x * blockDim.x + threadIdx.x;
    if (p >= S4) return;
    int b  = p / HW4;
    int hw = p - b * HW4;
    const float* flb = fl + (size_t)b * Cc * HW4 + hw;
    const float* frb = fr + (size_t)b * Cc * HW4 + hw;
    float ls = 0.f, rs = 0.f;
#pragma unroll
    for (int c = 0; c < Cc; ++c) {
        ls = fmaf(wred[c],      flb[(size_t)c * HW4], ls);
        rs = fmaf(wred[Cc + c], frb[(size_t)c * HW4], rs);
    }
    Lred[p] = ls;
    Rred[p] = rs;
}

// ---------------------------------------------------------------------------
// Kernel B: one 64-thread block (1 wave) handles 64 pixels; thread-per-pixel.
// Rank via beat-count with ROLLED j-loop over LDS (small icache footprint);
// i-side keys stay in registers as distinct u64 order-keys (exact ties).
// ---------------------------------------------------------------------------
__global__ __launch_bounds__(64, 1) void k_topk(const float* __restrict__ att,
                       const float* __restrict__ Lred, const float* __restrict__ Rred,
                       float* __restrict__ oA4, float* __restrict__ oD4) {
    __shared__ float a_lds[D4c * 64];   // [d][tid]
    __shared__ int   bc_lds[D4c * 64];  // [d][tid]
    __shared__ float rrow[128];         // Rred[pix0-63 .. pix0+64]

    const int tid  = threadIdx.x;
    const int pix0 = blockIdx.x * 64;
    const int pix  = pix0 + tid;
    const int b    = pix0 / HW4;        // uniform: HW4 % 64 == 0
    const int hw   = pix - b * HW4;
    const int w    = hw % W4c;

    // R row segment shared by the wave (clamped; invalid entries masked later)
    int ri0 = pix0 - 63 + tid; ri0 = ri0 < 0 ? 0 : ri0;
    int ri1 = pix0 + 1 + tid;  ri1 = ri1 >= S4 ? S4 - 1 : ri1;
    const float r0 = Rred[ri0];
    const float r1 = Rred[ri1];
    const float L  = Lred[pix];

    // 48 att logits (independent coalesced loads; compiler hoists)
    const float* ap = att + (size_t)b * D4c * HW4 + hw;
    float av[D4c];
#pragma unroll
    for (int i = 0; i < D4c; ++i) av[i] = ap[(size_t)i * HW4];

    rrow[tid]      = r0;
    rrow[tid + 64] = r1;

    // keys + stage a into LDS; bc init
    float m = -3.0e38f;
    unsigned long long key[D4c];
    int bc[D4c];
#pragma unroll
    for (int i = 0; i < D4c; ++i) {
        float a = av[i];
        a_lds[i * 64 + tid] = a;
        m = fmaxf(m, a);
        unsigned u = __float_as_uint(a);
        u = ((int)u < 0) ? ~u : (u | 0x80000000u);
        key[i] = (((unsigned long long)u) << 32) | (unsigned)(63 - i);
        bc[i] = 0;
    }
    __syncthreads();

    // beat counts: bc[i] = #{j : key_j > key_i}; keys distinct -> exactly 24 sel
#pragma unroll 2
    for (int j = 0; j < D4c; ++j) {
        float a = a_lds[j * 64 + tid];
        unsigned u = __float_as_uint(a);
        u = ((int)u < 0) ? ~u : (u | 0x80000000u);
        const unsigned long long kj = (((unsigned long long)u) << 32) | (unsigned)(63 - j);
#pragma unroll
        for (int i = 0; i < D4c; ++i) bc[i] += (kj > key[i]) ? 1 : 0;
    }

#pragma unroll
    for (int i = 0; i < D4c; ++i) bc_lds[i * 64 + tid] = bc[i];

    // final pass (rolled): softmax sums, att regression, cost top-2
    const float NEG = -3.0e38f;
    float s = 0.f, s2 = 0.f, n2 = 0.f;
    float v1 = NEG, v2 = NEG;
    int   i1 = 0,   i2 = 0;
#pragma unroll 2
    for (int j = 0; j < D4c; ++j) {
        float e   = expf(a_lds[j * 64 + tid] - m);
        bool  sel = bc_lds[j * 64 + tid] < Kc;
        float R   = (w >= j) ? rrow[tid + 63 - j] : 0.f;
        s += e;
        float es = sel ? e : 0.f;
        s2 += es;
        n2 = fmaf(es, (float)j, n2);
        float c = sel ? e * (L + R) : NEG;
        bool g1 = c > v1;
        bool g2 = c > v2;
        float nv2 = g1 ? v1 : (g2 ? c : v2);
        int   ni2 = g1 ? i1 : (g2 ? j : i2);
        v1 = g1 ? c : v1;
        i1 = g1 ? j : i1;
        v2 = nv2;
        i2 = ni2;
    }
    const float r = expf((v2 - v1) / s);   // true cost delta = (v2-v1)/s
    oA4[pix] = n2 / s2;
    oD4[pix] = ((float)i1 + r * (float)i2) / (1.f + r);
}

// ---------------------------------------------------------------------------
// Kernel C: full-res superpixel-guided 4x upsample (both predictions fused).
// ---------------------------------------------------------------------------
__global__ void k_upsample(const float* __restrict__ spx,
                           const float* __restrict__ A4, const float* __restrict__ D4p,
                           float* __restrict__ oA1, float* __restrict__ oD1) {
    int t = blockIdx.x * blockDim.x + threadIdx.x;
    if (t >= S1) return;
    int b  = t / HW1;
    int yx = t - b * HW1;
    int y  = yx / Wc;
    int x  = yx - y * Wc;

    const float* sp = spx + (size_t)b * 9 * HW1 + yx;
    float v[9];
    float m = -3.0e38f;
#pragma unroll
    for (int j = 0; j < 9; ++j) { v[j] = sp[(size_t)j * HW1]; m = fmaxf(m, v[j]); }
    float s = 0.f;
#pragma unroll
    for (int j = 0; j < 9; ++j) { v[j] = expf(v[j] - m); s += v[j]; }

    const int y4 = y >> 2, x4 = x >> 2;
    const float* A4b = A4 + b * HW4;
    const float* D4b = D4p + b * HW4;
    float accA = 0.f, accD = 0.f;
#pragma unroll
    for (int dy = 0; dy < 3; ++dy) {
        int yy = y4 + dy - 1;
#pragma unroll
        for (int dx = 0; dx < 3; ++dx) {
            int xx = x4 + dx - 1;
            int j = dy * 3 + dx;
            if (yy >= 0 && yy < H4c && xx >= 0 && xx < W4c) {
                int p = yy * W4c + xx;
                accA = fmaf(v[j], A4b[p], accA);
                accD = fmaf(v[j], D4b[p], accD);
            }
        }
    }
    const float inv = 4.f / s;
    oA1[t] = accA * inv;
    oD1[t] = accD * inv;
}

extern "C" void kernel_launch(void* const* d_in, const int* in_sizes, int n_in,
                              void* d_out, int out_size, void* d_ws, size_t ws_size,
                              hipStream_t stream) {
    const float* att  = (const float*)d_in[0];  // [B,1,48,128,240]
    const float* fl   = (const float*)d_in[1];  // [B,16,128,240]
    const float* fr   = (const float*)d_in[2];  // [B,16,128,240]
    const float* wred = (const float*)d_in[3];  // [32]
    const float* spx  = (const float*)d_in[4];  // [B,9,512,960]

    float* out = (float*)d_out;
    float* oA4 = out;                 // pred_att_x4 [B,128,240]
    float* oA1 = out + S4;            // pred_att_x1 [B,512,960]
    float* oD4 = out + S4 + S1;       // pred_x4     [B,128,240]
    float* oD1 = out + 2 * S4 + S1;   // pred_x1     [B,512,960]

    // scratch for reduced feature maps (2 * 61440 floats = 480 KiB)
    float *Lred, *Rred;
    if (ws_size >= (size_t)2 * S4 * sizeof(float)) {
        Lred = (float*)d_ws;
        Rred = Lred + S4;
    } else {
        Lred = oA1;          // overwritten by k_upsample afterwards
        Rred = oA1 + S4;
    }

    k_featred<<<(S4 + 255) / 256, 256, 0, stream>>>(fl, fr, wred, Lred, Rred);
    k_topk<<<S4 / 64, 64, 0, stream>>>(att, Lred, Rred, oA4, oD4);
    k_upsample<<<(S1 + 255) / 256, 256, 0, stream>>>(spx, oA4, oD4, oA1, oD1);
}

// Round 4
// 39.656 us; speedup vs baseline: 1.8986x; 1.8986x over previous
//
#include <hip/hip_runtime.h>
#include <hip/hip_bf16.h>
#include <math.h>

#define Bc 2
#define Cc 16
#define D4c 48
#define Kc 24
#define Hc 512
#define Wc 960
#define H4c 128
#define W4c 240
#define HW4 (H4c * W4c)   // 30720
#define S4 (Bc * HW4)     // 61440
#define HW1 (Hc * Wc)     // 491520
#define S1 (Bc * HW1)     // 983040
#define DPT 12            // disparities per thread (48 / 4 groups)

// ---------------------------------------------------------------------------
// Kernel A: channel-reduce feat_l/feat_r with w_red -> Lred[p], Rred[p]
// cost_k(p) = att_prob_k * (Lred[p] + Rred[p - d_k])   (Rred term 0 if d>col)
// ---------------------------------------------------------------------------
__global__ void k_featred(const float* __restrict__ fl, const float* __restrict__ fr,
                          const float* __restrict__ wred,
                          float* __restrict__ Lred, float* __restrict__ Rred) {
    int p = blockIdx.x * blockDim.x + threadIdx.x;
    if (p >= S4) return;
    int b  = p / HW4;
    int hw = p - b * HW4;
    const float* flb = fl + (size_t)b * Cc * HW4 + hw;
    const float* frb = fr + (size_t)b * Cc * HW4 + hw;
    float ls = 0.f, rs = 0.f;
#pragma unroll
    for (int c = 0; c < Cc; ++c) {
        ls = fmaf(wred[c],      flb[(size_t)c * HW4], ls);
        rs = fmaf(wred[Cc + c], frb[(size_t)c * HW4], rs);
    }
    Lred[p] = ls;
    Rred[p] = rs;
}

// ---------------------------------------------------------------------------
// Kernel B: 4 threads per pixel (each owns 12 disparities); 16 pixels/wave.
// lane = q*16 + p.  Rank = 12x48 pair compares on exact f64 order-keys
// (kd = monotone_u32(a)*64 + (63-d): distinct keys -> exactly 24 selected,
// matching top_k's value-desc / index-asc rule bit-exactly).  Other groups'
// keys arrive via __shfl_xor (rolled 4-chunk loop, no LDS, small icache).
// ---------------------------------------------------------------------------
__global__ __launch_bounds__(256, 4) void k_topk(const float* __restrict__ att,
                       const float* __restrict__ Lred, const float* __restrict__ Rred,
                       float* __restrict__ oA4, float* __restrict__ oD4) {
    const int tid   = threadIdx.x;
    const int wv    = tid >> 6;
    const int lane  = tid & 63;
    const int q     = lane >> 4;     // disparity group (0..3)
    const int p     = lane & 15;     // pixel within wave
    const int pix   = blockIdx.x * 64 + wv * 16 + p;
    const int b     = pix / HW4;
    const int hw    = pix - b * HW4;
    const int col   = hw % W4c;
    const int dbase = q * DPT;

    // ---- 12 att logits (16 consecutive pixels per lane-group: coalesced) ----
    const float* ap = att + ((size_t)b * D4c + dbase) * HW4 + hw;
    float a[DPT];
#pragma unroll
    for (int i = 0; i < DPT; ++i) a[i] = ap[(size_t)i * HW4];

    // ---- global max over all 48 (own 12 + butterfly over q-groups) ----
    float m = a[0];
#pragma unroll
    for (int i = 1; i < DPT; ++i) m = fmaxf(m, a[i]);
    m = fmaxf(m, __shfl_xor(m, 16));
    m = fmaxf(m, __shfl_xor(m, 32));

    // ---- exact order-keys (38-bit integer, exact in f64) ----
    double kd[DPT];
#pragma unroll
    for (int i = 0; i < DPT; ++i) {
        unsigned u = __float_as_uint(a[i]);
        u = ((int)u < 0) ? ~u : (u | 0x80000000u);
        kd[i] = (double)u * 64.0 + (double)(63 - (dbase + i));
    }

    // ---- beat counts: bc[i] = #{j in 48 : key_j > key_i} ----
    int bc[DPT];
#pragma unroll
    for (int i = 0; i < DPT; ++i) bc[i] = 0;
#pragma unroll 1
    for (int c = 0; c < 4; ++c) {
        double kj[DPT];
#pragma unroll
        for (int j = 0; j < DPT; ++j) kj[j] = __shfl_xor(kd[j], c << 4);
#pragma unroll
        for (int i = 0; i < DPT; ++i) {
#pragma unroll
            for (int j = 0; j < DPT; ++j) bc[i] += (kj[j] > kd[i]) ? 1 : 0;
        }
    }

    // ---- softmax partials, att regression partials, cost top-2 (own 12) ----
    const float L  = Lred[pix];
    const float NEG = -3.0e38f;
    float s = 0.f, s2 = 0.f, n2 = 0.f;
    float v1 = NEG, v2 = NEG;
    int   i1 = 0,   i2v = 0;
#pragma unroll
    for (int i = 0; i < DPT; ++i) {
        const int d = dbase + i;
        float e = __expf(a[i] - m);
        s += e;
        bool sel = bc[i] < Kc;
        float es = sel ? e : 0.f;
        s2 += es;
        n2 = fmaf(es, (float)d, n2);
        int ridx = (col >= d) ? (pix - d) : pix;   // always-safe address
        float R = Rred[ridx];
        R = (col >= d) ? R : 0.f;
        float cst = sel ? e * (L + R) : NEG;
        bool g1 = cst > v1;
        bool g2 = cst > v2;
        float nv2 = g1 ? v1 : (g2 ? cst : v2);
        int   ni2 = g1 ? i1 : (g2 ? d : i2v);
        v1 = g1 ? cst : v1;
        i1 = g1 ? d : i1;
        v2 = nv2;
        i2v = ni2;
    }

    // ---- butterfly merge across the 4 q-groups ----
#pragma unroll
    for (int st = 16; st <= 32; st <<= 1) {
        s  += __shfl_xor(s,  st);
        s2 += __shfl_xor(s2, st);
        n2 += __shfl_xor(n2, st);
        float ov1 = __shfl_xor(v1, st); int oi1 = __shfl_xor(i1,  st);
        float ov2 = __shfl_xor(v2, st); int oi2 = __shfl_xor(i2v, st);
        bool bt = (ov1 > v1) || (ov1 == v1 && oi1 < i1);   // other top1 wins?
        float w1 = bt ? ov1 : v1;   int wi1 = bt ? oi1 : i1;
        float l1 = bt ? v1  : ov1;  int li1 = bt ? i1  : oi1;
        float w2 = bt ? ov2 : v2;   int wi2 = bt ? oi2 : i2v;
        bool b2 = (l1 > w2) || (l1 == w2 && li1 < wi2);
        v1 = w1; i1 = wi1;
        v2 = b2 ? l1 : w2;
        i2v = b2 ? li1 : wi2;
    }

    const float r = __expf((v2 - v1) / s);   // true cost delta = (v2-v1)/s
    if (q == 0) {
        oA4[pix] = n2 / s2;
        oD4[pix] = ((float)i1 + r * (float)i2v) / (1.f + r);
    }
}

// ---------------------------------------------------------------------------
// Kernel C: full-res superpixel-guided 4x upsample (both predictions fused).
// ---------------------------------------------------------------------------
__global__ void k_upsample(const float* __restrict__ spx,
                           const float* __restrict__ A4, const float* __restrict__ D4p,
                           float* __restrict__ oA1, float* __restrict__ oD1) {
    int t = blockIdx.x * blockDim.x + threadIdx.x;
    if (t >= S1) return;
    int b  = t / HW1;
    int yx = t - b * HW1;
    int y  = yx / Wc;
    int x  = yx - y * Wc;

    const float* sp = spx + (size_t)b * 9 * HW1 + yx;
    float v[9];
    float m = -3.0e38f;
#pragma unroll
    for (int j = 0; j < 9; ++j) { v[j] = sp[(size_t)j * HW1]; m = fmaxf(m, v[j]); }
    float s = 0.f;
#pragma unroll
    for (int j = 0; j < 9; ++j) { v[j] = expf(v[j] - m); s += v[j]; }

    const int y4 = y >> 2, x4 = x >> 2;
    const float* A4b = A4 + b * HW4;
    const float* D4b = D4p + b * HW4;
    float accA = 0.f, accD = 0.f;
#pragma unroll
    for (int dy = 0; dy < 3; ++dy) {
        int yy = y4 + dy - 1;
#pragma unroll
        for (int dx = 0; dx < 3; ++dx) {
            int xx = x4 + dx - 1;
            int j = dy * 3 + dx;
            if (yy >= 0 && yy < H4c && xx >= 0 && xx < W4c) {
                int p = yy * W4c + xx;
                accA = fmaf(v[j], A4b[p], accA);
                accD = fmaf(v[j], D4b[p], accD);
            }
        }
    }
    const float inv = 4.f / s;
    oA1[t] = accA * inv;
    oD1[t] = accD * inv;
}

extern "C" void kernel_launch(void* const* d_in, const int* in_sizes, int n_in,
                              void* d_out, int out_size, void* d_ws, size_t ws_size,
                              hipStream_t stream) {
    const float* att  = (const float*)d_in[0];  // [B,1,48,128,240]
    const float* fl   = (const float*)d_in[1];  // [B,16,128,240]
    const float* fr   = (const float*)d_in[2];  // [B,16,128,240]
    const float* wred = (const float*)d_in[3];  // [32]
    const float* spx  = (const float*)d_in[4];  // [B,9,512,960]

    float* out = (float*)d_out;
    float* oA4 = out;                 // pred_att_x4 [B,128,240]
    float* oA1 = out + S4;            // pred_att_x1 [B,512,960]
    float* oD4 = out + S4 + S1;       // pred_x4     [B,128,240]
    float* oD1 = out + 2 * S4 + S1;   // pred_x1     [B,512,960]

    // scratch for reduced feature maps (2 * 61440 floats = 480 KiB)
    float *Lred, *Rred;
    if (ws_size >= (size_t)2 * S4 * sizeof(float)) {
        Lred = (float*)d_ws;
        Rred = Lred + S4;
    } else {
        Lred = oA1;          // overwritten by k_upsample afterwards
        Rred = oA1 + S4;
    }

    k_featred<<<(S4 + 255) / 256, 256, 0, stream>>>(fl, fr, wred, Lred, Rred);
    k_topk<<<S4 / 64, 256, 0, stream>>>(att, Lred, Rred, oA4, oD4);
    k_upsample<<<(S1 + 255) / 256, 256, 0, stream>>>(spx, oA4, oD4, oA1, oD1);
}

// Round 5
// 33.829 us; speedup vs baseline: 2.2256x; 1.1723x over previous
//
#include <hip/hip_runtime.h>
#include <hip/hip_bf16.h>
#include <math.h>

#define Bc 2
#define Cc 16
#define D4c 48
#define Kc 24
#define Hc 512
#define Wc 960
#define H4c 128
#define W4c 240
#define HW4 (H4c * W4c)   // 30720
#define S4 (Bc * HW4)     // 61440
#define HW1 (Hc * Wc)     // 491520
#define S1 (Bc * HW1)     // 983040
#define Gg 8              // disparity groups (lanes per pixel)
#define DPT 6             // disparities per thread

// ---------------------------------------------------------------------------
// Kernel A: channel-reduce feat_l/feat_r with w_red -> Lred, Rred (float4).
// ---------------------------------------------------------------------------
__global__ __launch_bounds__(256) void k_featred(const float* __restrict__ fl,
                          const float* __restrict__ fr,
                          const float* __restrict__ wred,
                          float* __restrict__ Lred, float* __restrict__ Rred) {
    int t = blockIdx.x * blockDim.x + threadIdx.x;   // one thread per 4 pixels
    if (t >= S4 / 4) return;
    int p4 = t * 4;
    int b  = p4 / HW4;
    int hw = p4 - b * HW4;
    const float* flb = fl + (size_t)b * Cc * HW4 + hw;
    const float* frb = fr + (size_t)b * Cc * HW4 + hw;
    float4 ls = {0.f, 0.f, 0.f, 0.f}, rs = {0.f, 0.f, 0.f, 0.f};
#pragma unroll
    for (int c = 0; c < Cc; ++c) {
        float wl = wred[c], wr = wred[Cc + c];
        float4 l = *(const float4*)(flb + (size_t)c * HW4);
        float4 r = *(const float4*)(frb + (size_t)c * HW4);
        ls.x = fmaf(wl, l.x, ls.x); ls.y = fmaf(wl, l.y, ls.y);
        ls.z = fmaf(wl, l.z, ls.z); ls.w = fmaf(wl, l.w, ls.w);
        rs.x = fmaf(wr, r.x, rs.x); rs.y = fmaf(wr, r.y, rs.y);
        rs.z = fmaf(wr, r.z, rs.z); rs.w = fmaf(wr, r.w, rs.w);
    }
    *(float4*)(Lred + p4) = ls;
    *(float4*)(Rred + p4) = rs;
}

// ---------------------------------------------------------------------------
// Kernel B: 8 lanes per pixel (6 disparities each), 8 pixels per wave.
// Exact top-24 selection via all-pairs beat-count on u32 monotone keys;
// index-tiebreak folded into a per-chunk "u - 1" adjust (>= vs >), so each
// pair costs one v_cmp_gt_u32 + addc. Chunk loop rolled (small icache).
// ---------------------------------------------------------------------------
__global__ __launch_bounds__(256) void k_topk(const float* __restrict__ att,
                       const float* __restrict__ Lred, const float* __restrict__ Rred,
                       float* __restrict__ oA4, float* __restrict__ oD4) {
    const int tid  = threadIdx.x;
    const int wv   = tid >> 6;
    const int lane = tid & 63;
    const int q    = lane >> 3;      // disparity group 0..7
    const int p    = lane & 7;       // pixel within wave
    const int pix  = blockIdx.x * 32 + wv * 8 + p;
    const int b    = pix / HW4;      // uniform per block (HW4 % 32 == 0)
    const int hw   = pix - b * HW4;
    const int col  = hw % W4c;
    const int dbase = q * DPT;

    // ---- loads issued up front (independent; latency overlapped) ----
    const float* ap = att + ((size_t)b * D4c + dbase) * HW4 + hw;
    float a[DPT], RR[DPT];
#pragma unroll
    for (int i = 0; i < DPT; ++i) a[i] = ap[(size_t)i * HW4];
#pragma unroll
    for (int i = 0; i < DPT; ++i) {
        int d = dbase + i;
        RR[i] = Rred[(col >= d) ? (pix - d) : pix];   // masked at use
    }
    const float L = Lred[pix];

    // ---- u32 monotone order keys ----
    unsigned u[DPT];
#pragma unroll
    for (int i = 0; i < DPT; ++i) {
        unsigned r = __float_as_uint(a[i]);
        u[i] = ((int)r < 0) ? ~r : (r | 0x80000000u);
    }

    // ---- global max (for stable exp) ----
    float m = a[0];
#pragma unroll
    for (int i = 1; i < DPT; ++i) m = fmaxf(m, a[i]);
    m = fmaxf(m, __shfl_xor(m, 8));
    m = fmaxf(m, __shfl_xor(m, 16));
    m = fmaxf(m, __shfl_xor(m, 32));

    // ---- beat counts ----
    int bc[DPT];
#pragma unroll
    for (int i = 0; i < DPT; ++i) bc[i] = 0;
    // own group: pair (i<j): i beats j iff u[i] >= u[j] (index tiebreak)
#pragma unroll
    for (int i = 0; i < DPT; ++i) {
#pragma unroll
        for (int j = i + 1; j < DPT; ++j) {
            int c = (u[i] >= u[j]) ? 1 : 0;
            bc[j] += c;
            bc[i] += 1 - c;
        }
    }
    // cross groups: partner qp = q ^ c.  If qp < q, partner's indices are all
    // lower -> partner beats me on ties -> count (uj >= u[i]) == (uj > u[i]-1).
#pragma unroll 1
    for (int c = 1; c < Gg; ++c) {
        const unsigned adj = ((q ^ c) < q) ? 1u : 0u;
        unsigned ui2[DPT], uj[DPT];
#pragma unroll
        for (int i = 0; i < DPT; ++i) ui2[i] = u[i] - adj;
#pragma unroll
        for (int j = 0; j < DPT; ++j) uj[j] = __shfl_xor(u[j], c << 3);
#pragma unroll
        for (int i = 0; i < DPT; ++i) {
#pragma unroll
            for (int j = 0; j < DPT; ++j) bc[i] += (uj[j] > ui2[i]) ? 1 : 0;
        }
    }

    // ---- per-thread partials: softmax sums, att regression, cost top-2 ----
    const float NEG = -3.0e38f;
    float s = 0.f, s2 = 0.f, n2 = 0.f;
    float v1 = NEG, v2 = NEG;
    int   i1 = 0,   i2v = 0;
#pragma unroll
    for (int i = 0; i < DPT; ++i) {
        const int d = dbase + i;
        float e = __expf(a[i] - m);
        s += e;
        bool sel = bc[i] < Kc;
        float es = sel ? e : 0.f;
        s2 += es;
        n2 = fmaf(es, (float)d, n2);
        float R = (col >= d) ? RR[i] : 0.f;
        float cst = sel ? e * (L + R) : NEG;
        bool g1 = cst > v1;
        bool g2 = cst > v2;
        float nv2 = g1 ? v1 : (g2 ? cst : v2);
        int   ni2 = g1 ? i1 : (g2 ? d : i2v);
        v1 = g1 ? cst : v1;
        i1 = g1 ? d : i1;
        v2 = nv2;
        i2v = ni2;
    }

    // ---- butterfly merge across the 8 groups (offsets 8,16,32) ----
#pragma unroll
    for (int st = 8; st <= 32; st <<= 1) {
        s  += __shfl_xor(s,  st);
        s2 += __shfl_xor(s2, st);
        n2 += __shfl_xor(n2, st);
        float ov1 = __shfl_xor(v1, st); int oi1 = __shfl_xor(i1,  st);
        float ov2 = __shfl_xor(v2, st); int oi2 = __shfl_xor(i2v, st);
        bool bt = (ov1 > v1) || (ov1 == v1 && oi1 < i1);
        float w1 = bt ? ov1 : v1;   int wi1 = bt ? oi1 : i1;
        float l1 = bt ? v1  : ov1;  int li1 = bt ? i1  : oi1;
        float w2 = bt ? ov2 : v2;   int wi2 = bt ? oi2 : i2v;
        bool b2 = (l1 > w2) || (l1 == w2 && li1 < wi2);
        v1 = w1; i1 = wi1;
        v2 = b2 ? l1 : w2;
        i2v = b2 ? li1 : wi2;
    }

    const float r = __expf((v2 - v1) / s);   // true cost delta = (v2-v1)/s
    if (q == 0) {
        oA4[pix] = n2 / s2;
        oD4[pix] = ((float)i1 + r * (float)i2v) / (1.f + r);
    }
}

// ---------------------------------------------------------------------------
// Kernel C: superpixel-guided 4x upsample; one thread = 4 consecutive x
// (they share one coarse 3x3 neighborhood).  No max-sub (logits ~N(0,1)).
// ---------------------------------------------------------------------------
__global__ __launch_bounds__(256) void k_upsample(const float* __restrict__ spx,
                           const float* __restrict__ A4, const float* __restrict__ D4p,
                           float* __restrict__ oA1, float* __restrict__ oD1) {
    int t = blockIdx.x * blockDim.x + threadIdx.x;
    if (t >= S1 / 4) return;
    const int Wq  = Wc / 4;              // 240
    int xg  = t % Wq;
    int rem = t / Wq;                    // b*Hc + y
    int y   = rem % Hc;
    int b   = rem / Hc;
    int yx0 = y * Wc + xg * 4;

    const float* sp = spx + (size_t)b * 9 * HW1 + yx0;
    float4 e[9];
    float4 ssum = {0.f, 0.f, 0.f, 0.f};
#pragma unroll
    for (int j = 0; j < 9; ++j) {
        float4 v = *(const float4*)(sp + (size_t)j * HW1);
        e[j].x = __expf(v.x); e[j].y = __expf(v.y);
        e[j].z = __expf(v.z); e[j].w = __expf(v.w);
        ssum.x += e[j].x; ssum.y += e[j].y; ssum.z += e[j].z; ssum.w += e[j].w;
    }

    const int y4 = y >> 2, x4 = xg;
    const float* A4b = A4 + b * HW4;
    const float* D4b = D4p + b * HW4;
    float4 accA = {0.f, 0.f, 0.f, 0.f}, accD = {0.f, 0.f, 0.f, 0.f};
#pragma unroll
    for (int dy = 0; dy < 3; ++dy) {
        int yy = y4 + dy - 1;
#pragma unroll
        for (int dx = 0; dx < 3; ++dx) {
            int xx = x4 + dx - 1;
            int j = dy * 3 + dx;
            bool ok = (yy >= 0 && yy < H4c && xx >= 0 && xx < W4c);
            int pI = ok ? (yy * W4c + xx) : 0;
            float ca = ok ? A4b[pI] : 0.f;
            float cd = ok ? D4b[pI] : 0.f;
            accA.x = fmaf(e[j].x, ca, accA.x); accA.y = fmaf(e[j].y, ca, accA.y);
            accA.z = fmaf(e[j].z, ca, accA.z); accA.w = fmaf(e[j].w, ca, accA.w);
            accD.x = fmaf(e[j].x, cd, accD.x); accD.y = fmaf(e[j].y, cd, accD.y);
            accD.z = fmaf(e[j].z, cd, accD.z); accD.w = fmaf(e[j].w, cd, accD.w);
        }
    }
    float4 oA, oD;
    oA.x = accA.x * 4.f / ssum.x; oA.y = accA.y * 4.f / ssum.y;
    oA.z = accA.z * 4.f / ssum.z; oA.w = accA.w * 4.f / ssum.w;
    oD.x = accD.x * 4.f / ssum.x; oD.y = accD.y * 4.f / ssum.y;
    oD.z = accD.z * 4.f / ssum.z; oD.w = accD.w * 4.f / ssum.w;
    *(float4*)(oA1 + (size_t)b * HW1 + yx0) = oA;
    *(float4*)(oD1 + (size_t)b * HW1 + yx0) = oD;
}

extern "C" void kernel_launch(void* const* d_in, const int* in_sizes, int n_in,
                              void* d_out, int out_size, void* d_ws, size_t ws_size,
                              hipStream_t stream) {
    const float* att  = (const float*)d_in[0];  // [B,1,48,128,240]
    const float* fl   = (const float*)d_in[1];  // [B,16,128,240]
    const float* fr   = (const float*)d_in[2];  // [B,16,128,240]
    const float* wred = (const float*)d_in[3];  // [32]
    const float* spx  = (const float*)d_in[4];  // [B,9,512,960]

    float* out = (float*)d_out;
    float* oA4 = out;                 // pred_att_x4 [B,128,240]
    float* oA1 = out + S4;            // pred_att_x1 [B,512,960]
    float* oD4 = out + S4 + S1;       // pred_x4     [B,128,240]
    float* oD1 = out + 2 * S4 + S1;   // pred_x1     [B,512,960]

    float *Lred, *Rred;
    if (ws_size >= (size_t)2 * S4 * sizeof(float)) {
        Lred = (float*)d_ws;
        Rred = Lred + S4;
    } else {
        Lred = oA1;          // overwritten by k_upsample afterwards
        Rred = oA1 + S4;
    }

    k_featred<<<(S4 / 4 + 255) / 256, 256, 0, stream>>>(fl, fr, wred, Lred, Rred);
    k_topk<<<S4 / 32, 256, 0, stream>>>(att, Lred, Rred, oA4, oD4);
    k_upsample<<<(S1 / 4 + 255) / 256, 256, 0, stream>>>(spx, oA4, oD4, oA1, oD1);
}

// Round 6
// 33.482 us; speedup vs baseline: 2.2486x; 1.0103x over previous
//
#include <hip/hip_runtime.h>
#include <hip/hip_bf16.h>
#include <math.h>

#define Bc 2
#define Cc 16
#define D4c 48
#define Kc 24
#define Hc 512
#define Wc 960
#define H4c 128
#define W4c 240
#define HW4 (H4c * W4c)   // 30720
#define S4 (Bc * HW4)     // 61440
#define HW1 (Hc * Wc)     // 491520
#define S1 (Bc * HW1)     // 983040
#define Gg 8              // disparity groups (lanes per pixel)
#define DPT 6             // disparities per thread

// ---------------------------------------------------------------------------
// Kernel A: channel-reduce feat_l/feat_r with w_red -> Lred, Rred (float4).
// ---------------------------------------------------------------------------
__global__ __launch_bounds__(256) void k_featred(const float* __restrict__ fl,
                          const float* __restrict__ fr,
                          const float* __restrict__ wred,
                          float* __restrict__ Lred, float* __restrict__ Rred) {
    int t = blockIdx.x * blockDim.x + threadIdx.x;   // one thread per 4 pixels
    if (t >= S4 / 4) return;
    int p4 = t * 4;
    int b  = p4 / HW4;
    int hw = p4 - b * HW4;
    const float* flb = fl + (size_t)b * Cc * HW4 + hw;
    const float* frb = fr + (size_t)b * Cc * HW4 + hw;
    float4 ls = {0.f, 0.f, 0.f, 0.f}, rs = {0.f, 0.f, 0.f, 0.f};
#pragma unroll
    for (int c = 0; c < Cc; ++c) {
        float wl = wred[c], wr = wred[Cc + c];
        float4 l = *(const float4*)(flb + (size_t)c * HW4);
        float4 r = *(const float4*)(frb + (size_t)c * HW4);
        ls.x = fmaf(wl, l.x, ls.x); ls.y = fmaf(wl, l.y, ls.y);
        ls.z = fmaf(wl, l.z, ls.z); ls.w = fmaf(wl, l.w, ls.w);
        rs.x = fmaf(wr, r.x, rs.x); rs.y = fmaf(wr, r.y, rs.y);
        rs.z = fmaf(wr, r.z, rs.z); rs.w = fmaf(wr, r.w, rs.w);
    }
    *(float4*)(Lred + p4) = ls;
    *(float4*)(Rred + p4) = rs;
}

// ---------------------------------------------------------------------------
// Kernel B: 8 lanes per pixel (6 disparities each), 8 pixels per wave.
// Exact top-24 via all-pairs beat-count on u32 monotone keys; index-tiebreak
// folded into per-chunk "u-1" adjust.  __launch_bounds__(256,6) caps VGPRs
// at ~85 so 6 waves/SIMD stay resident (R3 showed the allocator balloons to
// 256 VGPRs on this code shape without a cap -> 2 waves/SIMD, latency naked).
// ---------------------------------------------------------------------------
__global__ __launch_bounds__(256, 6) void k_topk(const float* __restrict__ att,
                       const float* __restrict__ Lred, const float* __restrict__ Rred,
                       float* __restrict__ oA4, float* __restrict__ oD4) {
    const int tid  = threadIdx.x;
    const int wv   = tid >> 6;
    const int lane = tid & 63;
    const int q    = lane >> 3;      // disparity group 0..7
    const int p    = lane & 7;       // pixel within wave
    const int pix  = blockIdx.x * 32 + wv * 8 + p;
    const int b    = pix / HW4;      // uniform per block (HW4 % 32 == 0)
    const int hw   = pix - b * HW4;
    const int col  = hw % W4c;
    const int dbase = q * DPT;

    // ---- loads issued up front (independent; latency overlapped) ----
    const float* ap = att + ((size_t)b * D4c + dbase) * HW4 + hw;
    float a[DPT], RR[DPT];
#pragma unroll
    for (int i = 0; i < DPT; ++i) a[i] = ap[(size_t)i * HW4];
#pragma unroll
    for (int i = 0; i < DPT; ++i) {
        int d = dbase + i;
        RR[i] = Rred[(col >= d) ? (pix - d) : pix];   // masked at use
    }
    const float L = Lred[pix];

    // ---- u32 monotone order keys ----
    unsigned u[DPT];
#pragma unroll
    for (int i = 0; i < DPT; ++i) {
        unsigned r = __float_as_uint(a[i]);
        u[i] = ((int)r < 0) ? ~r : (r | 0x80000000u);
    }

    // ---- global max (for stable exp) ----
    float m = a[0];
#pragma unroll
    for (int i = 1; i < DPT; ++i) m = fmaxf(m, a[i]);
    m = fmaxf(m, __shfl_xor(m, 8));
    m = fmaxf(m, __shfl_xor(m, 16));
    m = fmaxf(m, __shfl_xor(m, 32));

    // ---- beat counts ----
    int bc[DPT];
#pragma unroll
    for (int i = 0; i < DPT; ++i) bc[i] = 0;
    // own group: pair (i<j): i beats j iff u[i] >= u[j] (index tiebreak)
#pragma unroll
    for (int i = 0; i < DPT; ++i) {
#pragma unroll
        for (int j = i + 1; j < DPT; ++j) {
            int c = (u[i] >= u[j]) ? 1 : 0;
            bc[j] += c;
            bc[i] += 1 - c;
        }
    }
    // cross groups: partner qp = q ^ c.  If qp < q, partner's indices are all
    // lower -> partner beats me on ties -> count (uj >= u[i]) == (uj > u[i]-1).
    // unroll 2: next round's shuffles overlap this round's 72 compares.
#pragma unroll 2
    for (int c = 1; c < Gg; ++c) {
        const unsigned adj = ((q ^ c) < q) ? 1u : 0u;
        unsigned ui2[DPT], uj[DPT];
#pragma unroll
        for (int i = 0; i < DPT; ++i) ui2[i] = u[i] - adj;
#pragma unroll
        for (int j = 0; j < DPT; ++j) uj[j] = __shfl_xor(u[j], c << 3);
#pragma unroll
        for (int i = 0; i < DPT; ++i) {
#pragma unroll
            for (int j = 0; j < DPT; ++j) bc[i] += (uj[j] > ui2[i]) ? 1 : 0;
        }
    }

    // ---- per-thread partials: softmax sums, att regression, cost top-2 ----
    const float NEG = -3.0e38f;
    float s = 0.f, s2 = 0.f, n2 = 0.f;
    float v1 = NEG, v2 = NEG;
    int   i1 = 0,   i2v = 0;
#pragma unroll
    for (int i = 0; i < DPT; ++i) {
        const int d = dbase + i;
        float e = __expf(a[i] - m);
        s += e;
        bool sel = bc[i] < Kc;
        float es = sel ? e : 0.f;
        s2 += es;
        n2 = fmaf(es, (float)d, n2);
        float R = (col >= d) ? RR[i] : 0.f;
        float cst = sel ? e * (L + R) : NEG;
        bool g1 = cst > v1;
        bool g2 = cst > v2;
        float nv2 = g1 ? v1 : (g2 ? cst : v2);
        int   ni2 = g1 ? i1 : (g2 ? d : i2v);
        v1 = g1 ? cst : v1;
        i1 = g1 ? d : i1;
        v2 = nv2;
        i2v = ni2;
    }

    // ---- butterfly merge across the 8 groups (offsets 8,16,32) ----
#pragma unroll
    for (int st = 8; st <= 32; st <<= 1) {
        s  += __shfl_xor(s,  st);
        s2 += __shfl_xor(s2, st);
        n2 += __shfl_xor(n2, st);
        float ov1 = __shfl_xor(v1, st); int oi1 = __shfl_xor(i1,  st);
        float ov2 = __shfl_xor(v2, st); int oi2 = __shfl_xor(i2v, st);
        bool bt = (ov1 > v1) || (ov1 == v1 && oi1 < i1);
        float w1 = bt ? ov1 : v1;   int wi1 = bt ? oi1 : i1;
        float l1 = bt ? v1  : ov1;  int li1 = bt ? i1  : oi1;
        float w2 = bt ? ov2 : v2;   int wi2 = bt ? oi2 : i2v;
        bool b2 = (l1 > w2) || (l1 == w2 && li1 < wi2);
        v1 = w1; i1 = wi1;
        v2 = b2 ? l1 : w2;
        i2v = b2 ? li1 : wi2;
    }

    const float r = __expf((v2 - v1) / s);   // true cost delta = (v2-v1)/s
    if (q == 0) {
        oA4[pix] = n2 / s2;
        oD4[pix] = ((float)i1 + r * (float)i2v) / (1.f + r);
    }
}

// ---------------------------------------------------------------------------
// Kernel C: superpixel-guided 4x upsample; one thread = 4 consecutive x
// (they share one coarse 3x3 neighborhood).  No max-sub (logits ~N(0,1)).
// ---------------------------------------------------------------------------
__global__ __launch_bounds__(256) void k_upsample(const float* __restrict__ spx,
                           const float* __restrict__ A4, const float* __restrict__ D4p,
                           float* __restrict__ oA1, float* __restrict__ oD1) {
    int t = blockIdx.x * blockDim.x + threadIdx.x;
    if (t >= S1 / 4) return;
    const int Wq  = Wc / 4;              // 240
    int xg  = t % Wq;
    int rem = t / Wq;                    // b*Hc + y
    int y   = rem % Hc;
    int b   = rem / Hc;
    int yx0 = y * Wc + xg * 4;

    const float* sp = spx + (size_t)b * 9 * HW1 + yx0;
    float4 e[9];
    float4 ssum = {0.f, 0.f, 0.f, 0.f};
#pragma unroll
    for (int j = 0; j < 9; ++j) {
        float4 v = *(const float4*)(sp + (size_t)j * HW1);
        e[j].x = __expf(v.x); e[j].y = __expf(v.y);
        e[j].z = __expf(v.z); e[j].w = __expf(v.w);
        ssum.x += e[j].x; ssum.y += e[j].y; ssum.z += e[j].z; ssum.w += e[j].w;
    }

    const int y4 = y >> 2, x4 = xg;
    const float* A4b = A4 + b * HW4;
    const float* D4b = D4p + b * HW4;
    float4 accA = {0.f, 0.f, 0.f, 0.f}, accD = {0.f, 0.f, 0.f, 0.f};
#pragma unroll
    for (int dy = 0; dy < 3; ++dy) {
        int yy = y4 + dy - 1;
#pragma unroll
        for (int dx = 0; dx < 3; ++dx) {
            int xx = x4 + dx - 1;
            int j = dy * 3 + dx;
            bool ok = (yy >= 0 && yy < H4c && xx >= 0 && xx < W4c);
            int pI = ok ? (yy * W4c + xx) : 0;
            float ca = ok ? A4b[pI] : 0.f;
            float cd = ok ? D4b[pI] : 0.f;
            accA.x = fmaf(e[j].x, ca, accA.x); accA.y = fmaf(e[j].y, ca, accA.y);
            accA.z = fmaf(e[j].z, ca, accA.z); accA.w = fmaf(e[j].w, ca, accA.w);
            accD.x = fmaf(e[j].x, cd, accD.x); accD.y = fmaf(e[j].y, cd, accD.y);
            accD.z = fmaf(e[j].z, cd, accD.z); accD.w = fmaf(e[j].w, cd, accD.w);
        }
    }
    float4 inv;
    inv.x = 4.f / ssum.x; inv.y = 4.f / ssum.y;
    inv.z = 4.f / ssum.z; inv.w = 4.f / ssum.w;
    float4 oA, oD;
    oA.x = accA.x * inv.x; oA.y = accA.y * inv.y;
    oA.z = accA.z * inv.z; oA.w = accA.w * inv.w;
    oD.x = accD.x * inv.x; oD.y = accD.y * inv.y;
    oD.z = accD.z * inv.z; oD.w = accD.w * inv.w;
    *(float4*)(oA1 + (size_t)b * HW1 + yx0) = oA;
    *(float4*)(oD1 + (size_t)b * HW1 + yx0) = oD;
}

extern "C" void kernel_launch(void* const* d_in, const int* in_sizes, int n_in,
                              void* d_out, int out_size, void* d_ws, size_t ws_size,
                              hipStream_t stream) {
    const float* att  = (const float*)d_in[0];  // [B,1,48,128,240]
    const float* fl   = (const float*)d_in[1];  // [B,16,128,240]
    const float* fr   = (const float*)d_in[2];  // [B,16,128,240]
    const float* wred = (const float*)d_in[3];  // [32]
    const float* spx  = (const float*)d_in[4];  // [B,9,512,960]

    float* out = (float*)d_out;
    float* oA4 = out;                 // pred_att_x4 [B,128,240]
    float* oA1 = out + S4;            // pred_att_x1 [B,512,960]
    float* oD4 = out + S4 + S1;       // pred_x4     [B,128,240]
    float* oD1 = out + 2 * S4 + S1;   // pred_x1     [B,512,960]

    float *Lred, *Rred;
    if (ws_size >= (size_t)2 * S4 * sizeof(float)) {
        Lred = (float*)d_ws;
        Rred = Lred + S4;
    } else {
        Lred = oA1;          // overwritten by k_upsample afterwards
        Rred = oA1 + S4;
    }

    k_featred<<<(S4 / 4 + 255) / 256, 256, 0, stream>>>(fl, fr, wred, Lred, Rred);
    k_topk<<<S4 / 32, 256, 0, stream>>>(att, Lred, Rred, oA4, oD4);
    k_upsample<<<(S1 / 4 + 255) / 256, 256, 0, stream>>>(spx, oA4, oD4, oA1, oD1);
}

// Round 7
// 31.426 us; speedup vs baseline: 2.3957x; 1.0654x over previous
//
#include <hip/hip_runtime.h>
#include <hip/hip_bf16.h>
#include <math.h>

#define Bc 2
#define Cc 16
#define D4c 48
#define Kc 24
#define Hc 512
#define Wc 960
#define H4c 128
#define W4c 240
#define HW4 (H4c * W4c)   // 30720
#define S4 (Bc * HW4)     // 61440
#define HW1 (Hc * Wc)     // 491520
#define S1 (Bc * HW1)     // 983040
#define Gg 8              // disparity groups (lanes per pixel)
#define DPT 6             // disparities per thread
#define PPB 32            // pixels per block
#define HALO 47           // max disparity reach to the left
#define RW (PPB + HALO)   // 79: Rred halo row length

// ---------------------------------------------------------------------------
// Kernel B (fused): per block of 32 pixels, first compute Lred/Rred rows in
// LDS from feat_l/feat_r (channel-reduction with w_red; halo re-reads are L2
// hits), then 8-lanes-per-pixel exact top-24 + both regressions.
// ---------------------------------------------------------------------------
__global__ __launch_bounds__(256, 6) void k_topk(const float* __restrict__ att,
                       const float* __restrict__ fl, const float* __restrict__ fr,
                       const float* __restrict__ wred,
                       float* __restrict__ oA4, float* __restrict__ oD4) {
    __shared__ float rrow[RW];   // Rred[pix0-47 .. pix0+31]
    __shared__ float lrow[PPB];  // Lred[pix0 .. pix0+31]

    const int tid   = threadIdx.x;
    const int wv    = tid >> 6;
    const int lane  = tid & 63;
    const int q     = lane >> 3;      // disparity group 0..7
    const int p     = lane & 7;       // pixel within wave
    const int plocal = wv * 8 + p;    // 0..31
    const int pix0  = blockIdx.x * PPB;
    const int pix   = pix0 + plocal;
    const int b     = pix0 / HW4;     // uniform per block (HW4 % 32 == 0)
    const int hw    = pix - b * HW4;
    const int col   = hw % W4c;
    const int dbase = q * DPT;

    // ---- att loads issued first (latency overlapped with feat stage) ----
    const float* ap = att + ((size_t)b * D4c + dbase) * HW4 + hw;
    float a[DPT];
#pragma unroll
    for (int i = 0; i < DPT; ++i) a[i] = ap[(size_t)i * HW4];

    // ---- feat channel-reduction into LDS (threads 0..110) ----
    {
        const int base = b * HW4;
        if (tid < RW) {
            int lin = pix0 - HALO + tid;
            if (lin < base) lin = base;            // clamped values never used
            const float* frb = fr + (size_t)b * Cc * HW4 + (lin - base);
            float acc = 0.f;
#pragma unroll
            for (int c = 0; c < Cc; ++c)
                acc = fmaf(wred[Cc + c], frb[(size_t)c * HW4], acc);
            rrow[tid] = acc;
        } else if (tid < RW + PPB) {
            int j = tid - RW;                      // 0..31
            const float* flb = fl + (size_t)b * Cc * HW4 + (pix0 + j - base);
            float acc = 0.f;
#pragma unroll
            for (int c = 0; c < Cc; ++c)
                acc = fmaf(wred[c], flb[(size_t)c * HW4], acc);
            lrow[j] = acc;
        }
    }
    __syncthreads();

    const float L = lrow[plocal];
    float RR[DPT];
#pragma unroll
    for (int i = 0; i < DPT; ++i) {
        int d = dbase + i;
        int idx = HALO + plocal - d;
        RR[i] = rrow[(col >= d) ? idx : HALO + plocal];   // masked at use
    }

    // ---- u32 monotone order keys ----
    unsigned u[DPT];
#pragma unroll
    for (int i = 0; i < DPT; ++i) {
        unsigned r = __float_as_uint(a[i]);
        u[i] = ((int)r < 0) ? ~r : (r | 0x80000000u);
    }

    // ---- global max (for stable exp) ----
    float m = a[0];
#pragma unroll
    for (int i = 1; i < DPT; ++i) m = fmaxf(m, a[i]);
    m = fmaxf(m, __shfl_xor(m, 8));
    m = fmaxf(m, __shfl_xor(m, 16));
    m = fmaxf(m, __shfl_xor(m, 32));

    // ---- beat counts ----
    int bc[DPT];
#pragma unroll
    for (int i = 0; i < DPT; ++i) bc[i] = 0;
    // own group: pair (i<j): i beats j iff u[i] >= u[j] (index tiebreak)
#pragma unroll
    for (int i = 0; i < DPT; ++i) {
#pragma unroll
        for (int j = i + 1; j < DPT; ++j) {
            int c = (u[i] >= u[j]) ? 1 : 0;
            bc[j] += c;
            bc[i] += 1 - c;
        }
    }
    // cross groups: partner qp = q ^ c.  If qp < q, partner's indices are all
    // lower -> partner beats me on ties -> count (uj >= u[i]) == (uj > u[i]-1).
#pragma unroll 2
    for (int c = 1; c < Gg; ++c) {
        const unsigned adj = ((q ^ c) < q) ? 1u : 0u;
        unsigned ui2[DPT], uj[DPT];
#pragma unroll
        for (int i = 0; i < DPT; ++i) ui2[i] = u[i] - adj;
#pragma unroll
        for (int j = 0; j < DPT; ++j) uj[j] = __shfl_xor(u[j], c << 3);
#pragma unroll
        for (int i = 0; i < DPT; ++i) {
#pragma unroll
            for (int j = 0; j < DPT; ++j) bc[i] += (uj[j] > ui2[i]) ? 1 : 0;
        }
    }

    // ---- per-thread partials: softmax sums, att regression, cost top-2 ----
    const float NEG = -3.0e38f;
    float s = 0.f, s2 = 0.f, n2 = 0.f;
    float v1 = NEG, v2 = NEG;
    int   i1 = 0,   i2v = 0;
#pragma unroll
    for (int i = 0; i < DPT; ++i) {
        const int d = dbase + i;
        float e = __expf(a[i] - m);
        s += e;
        bool sel = bc[i] < Kc;
        float es = sel ? e : 0.f;
        s2 += es;
        n2 = fmaf(es, (float)d, n2);
        float R = (col >= d) ? RR[i] : 0.f;
        float cst = sel ? e * (L + R) : NEG;
        bool g1 = cst > v1;
        bool g2 = cst > v2;
        float nv2 = g1 ? v1 : (g2 ? cst : v2);
        int   ni2 = g1 ? i1 : (g2 ? d : i2v);
        v1 = g1 ? cst : v1;
        i1 = g1 ? d : i1;
        v2 = nv2;
        i2v = ni2;
    }

    // ---- butterfly merge across the 8 groups (offsets 8,16,32) ----
#pragma unroll
    for (int st = 8; st <= 32; st <<= 1) {
        s  += __shfl_xor(s,  st);
        s2 += __shfl_xor(s2, st);
        n2 += __shfl_xor(n2, st);
        float ov1 = __shfl_xor(v1, st); int oi1 = __shfl_xor(i1,  st);
        float ov2 = __shfl_xor(v2, st); int oi2 = __shfl_xor(i2v, st);
        bool bt = (ov1 > v1) || (ov1 == v1 && oi1 < i1);
        float w1 = bt ? ov1 : v1;   int wi1 = bt ? oi1 : i1;
        float l1 = bt ? v1  : ov1;  int li1 = bt ? i1  : oi1;
        float w2 = bt ? ov2 : v2;   int wi2 = bt ? oi2 : i2v;
        bool b2 = (l1 > w2) || (l1 == w2 && li1 < wi2);
        v1 = w1; i1 = wi1;
        v2 = b2 ? l1 : w2;
        i2v = b2 ? li1 : wi2;
    }

    const float r = __expf((v2 - v1) / s);   // true cost delta = (v2-v1)/s
    if (q == 0) {
        oA4[pix] = n2 / s2;
        oD4[pix] = ((float)i1 + r * (float)i2v) / (1.f + r);
    }
}

// ---------------------------------------------------------------------------
// Kernel C: superpixel-guided 4x upsample; one thread = 4 consecutive x
// (they share one coarse 3x3 neighborhood).  No max-sub (logits ~N(0,1)).
// ---------------------------------------------------------------------------
__global__ __launch_bounds__(256) void k_upsample(const float* __restrict__ spx,
                           const float* __restrict__ A4, const float* __restrict__ D4p,
                           float* __restrict__ oA1, float* __restrict__ oD1) {
    int t = blockIdx.x * blockDim.x + threadIdx.x;
    if (t >= S1 / 4) return;
    const int Wq  = Wc / 4;              // 240
    int xg  = t % Wq;
    int rem = t / Wq;                    // b*Hc + y
    int y   = rem % Hc;
    int b   = rem / Hc;
    int yx0 = y * Wc + xg * 4;

    const float* sp = spx + (size_t)b * 9 * HW1 + yx0;
    float4 e[9];
    float4 ssum = {0.f, 0.f, 0.f, 0.f};
#pragma unroll
    for (int j = 0; j < 9; ++j) {
        float4 v = *(const float4*)(sp + (size_t)j * HW1);
        e[j].x = __expf(v.x); e[j].y = __expf(v.y);
        e[j].z = __expf(v.z); e[j].w = __expf(v.w);
        ssum.x += e[j].x; ssum.y += e[j].y; ssum.z += e[j].z; ssum.w += e[j].w;
    }

    const int y4 = y >> 2, x4 = xg;
    const float* A4b = A4 + b * HW4;
    const float* D4b = D4p + b * HW4;
    float4 accA = {0.f, 0.f, 0.f, 0.f}, accD = {0.f, 0.f, 0.f, 0.f};
#pragma unroll
    for (int dy = 0; dy < 3; ++dy) {
        int yy = y4 + dy - 1;
#pragma unroll
        for (int dx = 0; dx < 3; ++dx) {
            int xx = x4 + dx - 1;
            int j = dy * 3 + dx;
            bool ok = (yy >= 0 && yy < H4c && xx >= 0 && xx < W4c);
            int pI = ok ? (yy * W4c + xx) : 0;
            float ca = ok ? A4b[pI] : 0.f;
            float cd = ok ? D4b[pI] : 0.f;
            accA.x = fmaf(e[j].x, ca, accA.x); accA.y = fmaf(e[j].y, ca, accA.y);
            accA.z = fmaf(e[j].z, ca, accA.z); accA.w = fmaf(e[j].w, ca, accA.w);
            accD.x = fmaf(e[j].x, cd, accD.x); accD.y = fmaf(e[j].y, cd, accD.y);
            accD.z = fmaf(e[j].z, cd, accD.z); accD.w = fmaf(e[j].w, cd, accD.w);
        }
    }
    float4 inv;
    inv.x = 4.f * __builtin_amdgcn_rcpf(ssum.x);
    inv.y = 4.f * __builtin_amdgcn_rcpf(ssum.y);
    inv.z = 4.f * __builtin_amdgcn_rcpf(ssum.z);
    inv.w = 4.f * __builtin_amdgcn_rcpf(ssum.w);
    float4 oA, oD;
    oA.x = accA.x * inv.x; oA.y = accA.y * inv.y;
    oA.z = accA.z * inv.z; oA.w = accA.w * inv.w;
    oD.x = accD.x * inv.x; oD.y = accD.y * inv.y;
    oD.z = accD.z * inv.z; oD.w = accD.w * inv.w;
    *(float4*)(oA1 + (size_t)b * HW1 + yx0) = oA;
    *(float4*)(oD1 + (size_t)b * HW1 + yx0) = oD;
}

extern "C" void kernel_launch(void* const* d_in, const int* in_sizes, int n_in,
                              void* d_out, int out_size, void* d_ws, size_t ws_size,
                              hipStream_t stream) {
    const float* att  = (const float*)d_in[0];  // [B,1,48,128,240]
    const float* fl   = (const float*)d_in[1];  // [B,16,128,240]
    const float* fr   = (const float*)d_in[2];  // [B,16,128,240]
    const float* wred = (const float*)d_in[3];  // [32]
    const float* spx  = (const float*)d_in[4];  // [B,9,512,960]

    float* out = (float*)d_out;
    float* oA4 = out;                 // pred_att_x4 [B,128,240]
    float* oA1 = out + S4;            // pred_att_x1 [B,512,960]
    float* oD4 = out + S4 + S1;       // pred_x4     [B,128,240]
    float* oD1 = out + 2 * S4 + S1;   // pred_x1     [B,512,960]

    k_topk<<<S4 / PPB, 256, 0, stream>>>(att, fl, fr, wred, oA4, oD4);
    k_upsample<<<(S1 / 4 + 255) / 256, 256, 0, stream>>>(spx, oA4, oD4, oA1, oD1);
}